// Round 7
// baseline (188.931 us; speedup 1.0000x reference)
//
#include <hip/hip_runtime.h>
#include <hip/hip_bf16.h>

// AttentionGrouping: B=4096 graphs, N=32 nodes, D=128, H=2 heads.
// Inputs fp32, outputs fp32: out=[B*N,128] then weight=[B*N,32,2] in d_out.
//
// R11: register-resident bitonic sparsemax. Phase 3 was ~80% of VALU
// (1120/lane: 8 rows x 32 elems x 4 VALU + f32 div) and VALU is ~62% of
// saturation. Replace with: per quad (16 lanes) sort its own row's 32 cols
// held in sacc regs (e = jt*16+lrow) via width-16 shfl_xor bitonic
// (keepmax = bit_d(e)==bit_k(e), desk-checked; d=16 stage = in-lane reg
// swap), Kogge-Stone inclusive cumsum, tau = max_k (cum_k-1)/k with
// precomputed rcp (no div), w = relu(z - tau) from untouched sacc.
// 4 rows/pass x 4 passes = 16 rows/wave. Deletes the whole s_s f32 buffer
// + spill + 72 broadcast reads/lane; w (bf16) written once into dead t_s
// region (w_s [64][40]). VALU/lane ~1300 -> ~660. LDS stays 32768 (5-blk
// ceiling), 5 barriers, phases 0-2a identical to R10 (proven).

#define NG 4096

typedef short bf16x8 __attribute__((ext_vector_type(8)));
typedef short bf16x4 __attribute__((ext_vector_type(4)));
typedef float f32x4 __attribute__((ext_vector_type(4)));

__device__ inline short f2bf(float f) {
    __hip_bfloat16 h = __float2bfloat16(f);
    return __builtin_bit_cast(short, h);
}
__device__ inline float bf2f(short s) {
    return __builtin_bit_cast(float, ((unsigned)(unsigned short)s) << 16);
}
__device__ inline unsigned pack2(float a, float b) {
    return (unsigned)(unsigned short)f2bf(a) | ((unsigned)(unsigned short)f2bf(b) << 16);
}

// t_s swizzle: [32 node][256 d'] shorts, col ^= (node&7)<<3 (bits 3-5: keeps
// b64/b128 alignment, col stays in [0,256)).
#define TSWZ(node, col) ((((node) << 8)) + (((col) ^ (((node) & 7) << 3))))
// vT_s swizzle: [256 d'][32 node] shorts, idx ^= (row&3)<<3.
#define VSWZ(row, col) ((((row) << 5) + (col)) ^ (((row) & 3) << 3))
// x_l swizzle: [32 node][128 col] shorts, col ^= (node&7)<<3 (col in [0,128)).
#define XSWZ(node, col) (((node) << 7) + (((col) ^ (((node) & 7) << 3))))

// packed_m[(mt*4+s)*512 + lane*8 + jj] = bf16( (1/16)*sum_c WQ[a][h*128+c]*WK[bl][h*128+c] )
//   h = mt>>3, a = s*32+(lane>>4)*8+jj (k-dim of T-mfma), bl = (mt&7)*16+(lane&15)
// A-frag of M^T for T^T = M^T X^T.
// packed_v[(t*4+s)*512 + lane*8 + jj] = bf16(WV[s*32+(lane>>4)*8+jj][t*16+(lane&15)])
// B-frag of WV for V = X WV. Both packs in one launch.
__global__ void pack_mv_kernel(const float* __restrict__ WQ, const float* __restrict__ WK,
                               const float* __restrict__ WV,
                               short* __restrict__ pm, short* __restrict__ pv) {
    int gidx = blockIdx.x * 256 + threadIdx.x;    // 65536 total
    if (gidx < 32768) {
        int idx  = gidx;
        int jj   = idx & 7;
        int lane = (idx >> 3) & 63;
        int s    = (idx >> 9) & 3;
        int mt   = (idx >> 11) & 15;
        int h    = mt >> 3;
        int a    = s * 32 + (lane >> 4) * 8 + jj;
        int bl   = (mt & 7) * 16 + (lane & 15);
        const float4* qa = (const float4*)(WQ + a * 256 + h * 128);
        const float4* kb = (const float4*)(WK + bl * 256 + h * 128);
        float acc = 0.f;
        #pragma unroll 8
        for (int c = 0; c < 32; ++c) {
            float4 q4 = qa[c], k4 = kb[c];
            acc += q4.x * k4.x + q4.y * k4.y + q4.z * k4.z + q4.w * k4.w;
        }
        pm[idx] = f2bf(acc * 0.0625f);
    } else {
        int idx  = gidx - 32768;
        int jj   = idx & 7;
        int lane = (idx >> 3) & 63;
        int s    = (idx >> 9) & 3;
        int t    = (idx >> 11) & 15;
        int krow = s * 32 + (lane >> 4) * 8 + jj;
        int col  = t * 16 + (lane & 15);
        pv[idx] = f2bf(WV[krow * 256 + col]);
    }
}

__global__ __launch_bounds__(256, 4)
void fused_attn_kernel(const float* __restrict__ x, const short* __restrict__ pm,
                       const short* __restrict__ pv, float* __restrict__ out,
                       float* __restrict__ wgt) {
    __shared__ char __align__(16) smem[32768];
    short* x_l  = (short*)smem;               // x [32][128] bf16 swz, 8192 B (phase 0 only)
    short* t_s  = (short*)smem;               // T [32 node][256 d'] bf16 swz, 16384 B (ph 1a-2a)
    short* w_s  = (short*)smem;               // W [64 row][40] bf16, 5120 B (ph 3+) — over dead t_s
    short* vT_s = (short*)(smem + 16384);     // V^T [256 d'][32 node] bf16 swz, 16384 B

    int b    = blockIdx.x;
    int tid  = threadIdx.x;
    int lane = tid & 63;
    int wave = tid >> 6;
    int lrow = lane & 15;
    int quad = lane >> 4;

    // ---- phase 0: coalesced x -> bf16 x_l (one conversion per element) ----
    const float* xg = x + (size_t)b * 4096;
    #pragma unroll
    for (int i = 0; i < 4; ++i) {
        int flat4 = i * 256 + tid;            // float4 index 0..1023
        int node  = flat4 >> 5;
        int c4    = (flat4 & 31) * 4;
        float4 f  = *(const float4*)&xg[flat4 * 4];
        uint2 pk; pk.x = pack2(f.x, f.y); pk.y = pack2(f.z, f.w);
        *(uint2*)&x_l[XSWZ(node, c4)] = pk;
    }
    __syncthreads();

    // ---- x_l -> register fragments ----
    bf16x8 xf[2][4];                          // [node-tile][k-chunk]
    #pragma unroll
    for (int nt = 0; nt < 2; ++nt)
        #pragma unroll
        for (int s = 0; s < 4; ++s)
            xf[nt][s] = *(const bf16x8*)&x_l[XSWZ(nt * 16 + lrow, s * 32 + quad * 8)];
    __syncthreads();                          // x_l dead; t_s region writable

    // ---- phase 1a: T^T = M^T X^T -> t_s[node][d'] (swizzled) via packed b64 stores ----
    #pragma unroll
    for (int t = 0; t < 4; ++t) {
        int mt = wave * 4 + t;                // d'-tile 0..15 (head = mt>>3)
        const short* pb = pm + (mt * 4) * 512 + lane * 8;
        bf16x8 wf[4];
        #pragma unroll
        for (int s = 0; s < 4; ++s) wf[s] = *(const bf16x8*)&pb[s * 512];
        f32x4 acc[2] = {{0.f,0.f,0.f,0.f},{0.f,0.f,0.f,0.f}};
        #pragma unroll
        for (int nt = 0; nt < 2; ++nt)
            #pragma unroll
            for (int s = 0; s < 4; ++s)
                acc[nt] = __builtin_amdgcn_mfma_f32_16x16x32_bf16(wf[s], xf[nt][s], acc[nt], 0, 0, 0);
        #pragma unroll
        for (int nt = 0; nt < 2; ++nt) {
            int node = nt * 16 + lrow;
            int addr = TSWZ(node, mt * 16 + quad * 4);
            uint2 pk; pk.x = pack2(acc[nt][0], acc[nt][1]); pk.y = pack2(acc[nt][2], acc[nt][3]);
            *(uint2*)&t_s[addr] = pk;
        }
    }
    // ---- phase 1b: V = X WV -> vT_s[d'][node] (swizzled) via packed b64 stores ----
    #pragma unroll
    for (int t = 0; t < 4; ++t) {
        int ntv = wave * 4 + t;               // d'-col-tile 0..15
        const short* pb = pv + (ntv * 4) * 512 + lane * 8;
        bf16x8 wf[4];
        #pragma unroll
        for (int s = 0; s < 4; ++s) wf[s] = *(const bf16x8*)&pb[s * 512];
        f32x4 acc[2] = {{0.f,0.f,0.f,0.f},{0.f,0.f,0.f,0.f}};
        #pragma unroll
        for (int mt = 0; mt < 2; ++mt)
            #pragma unroll
            for (int s = 0; s < 4; ++s)
                acc[mt] = __builtin_amdgcn_mfma_f32_16x16x32_bf16(xf[mt][s], wf[s], acc[mt], 0, 0, 0);
        #pragma unroll
        for (int mt = 0; mt < 2; ++mt) {
            int row = ntv * 16 + lrow;
            int idx = VSWZ(row, mt * 16 + quad * 4);
            uint2 pk; pk.x = pack2(acc[mt][0], acc[mt][1]); pk.y = pack2(acc[mt][2], acc[mt][3]);
            *(uint2*)&vT_s[idx] = pk;
        }
    }
    __syncthreads();

    // ---- phase 2a: S_h = T_h X^T -> registers. Wave w: h = w>>1, it = w&1.
    //      sacc[jt][r] = S[row_local = quad*4+r][col = jt*16+lrow]. ----
    f32x4 sacc[2];
    #pragma unroll
    for (int jt = 0; jt < 2; ++jt) {
        int h = wave >> 1, it = wave & 1;
        f32x4 acc = {0.f, 0.f, 0.f, 0.f};
        #pragma unroll
        for (int s = 0; s < 4; ++s) {
            int node = it * 16 + lrow;
            bf16x8 at = *(const bf16x8*)&t_s[TSWZ(node, h * 128 + s * 32 + quad * 8)];
            acc = __builtin_amdgcn_mfma_f32_16x16x32_bf16(at, xf[jt][s], acc, 0, 0, 0);
        }
        sacc[jt] = acc;
    }
    __syncthreads();                          // all t_s reads done; w_s region writable

    // ---- phase 3: register bitonic sparsemax. Each quad (16 lanes) owns row
    //      quad*4+r per pass; its 32 cols live in sacc[0][r] (e=lrow) and
    //      sacc[1][r] (e=16+lrow). Descending bitonic: keepmax(e; k,d) =
    //      (bit_d(e) == bit_k(e)). d=16 stage = in-lane swap. Then inclusive
    //      cumsum (Kogge-Stone), tau = max_k (cum_k - 1)/k (rcp, no div),
    //      w = relu(z - tau) from untouched sacc. ----
    {
        float rk0 = __builtin_amdgcn_rcpf((float)(lrow + 1));
        float rk1 = __builtin_amdgcn_rcpf((float)(lrow + 17));
        int b0 = (lrow >> 0) & 1, b1 = (lrow >> 1) & 1;
        int b2 = (lrow >> 2) & 1, b3 = (lrow >> 3) & 1;
        bool e01 = b0 == b1;                  // k=2,  d=1
        bool e12 = b1 == b2;                  // k=4,  d=2
        bool e02 = b0 == b2;                  // k=4,  d=1
        bool e23 = b2 == b3;                  // k=8,  d=4
        bool e13 = b1 == b3;                  // k=8,  d=2
        bool e03 = b0 == b3;                  // k=8,  d=1
        bool a0 = b0 == 0, a1 = b1 == 0, a2 = b2 == 0, a3 = b3 == 0;

        #pragma unroll
        for (int r = 0; r < 4; ++r) {
            float v0 = sacc[0][r], v1 = sacc[1][r];
            float p;
            // k=2
            p = __shfl_xor(v0, 1, 16); v0 = e01 ? fmaxf(v0, p) : fminf(v0, p);
            p = __shfl_xor(v1, 1, 16); v1 = e01 ? fmaxf(v1, p) : fminf(v1, p);
            // k=4
            p = __shfl_xor(v0, 2, 16); v0 = e12 ? fmaxf(v0, p) : fminf(v0, p);
            p = __shfl_xor(v1, 2, 16); v1 = e12 ? fmaxf(v1, p) : fminf(v1, p);
            p = __shfl_xor(v0, 1, 16); v0 = e02 ? fmaxf(v0, p) : fminf(v0, p);
            p = __shfl_xor(v1, 1, 16); v1 = e02 ? fmaxf(v1, p) : fminf(v1, p);
            // k=8
            p = __shfl_xor(v0, 4, 16); v0 = e23 ? fmaxf(v0, p) : fminf(v0, p);
            p = __shfl_xor(v1, 4, 16); v1 = e23 ? fmaxf(v1, p) : fminf(v1, p);
            p = __shfl_xor(v0, 2, 16); v0 = e13 ? fmaxf(v0, p) : fminf(v0, p);
            p = __shfl_xor(v1, 2, 16); v1 = e13 ? fmaxf(v1, p) : fminf(v1, p);
            p = __shfl_xor(v0, 1, 16); v0 = e03 ? fmaxf(v0, p) : fminf(v0, p);
            p = __shfl_xor(v1, 1, 16); v1 = e03 ? fmaxf(v1, p) : fminf(v1, p);
            // k=16 (bit4(e) = reg index: reg0 keepmax = a_d, reg1 inverted)
            p = __shfl_xor(v0, 8, 16); v0 = a3 ? fmaxf(v0, p) : fminf(v0, p);
            p = __shfl_xor(v1, 8, 16); v1 = a3 ? fminf(v1, p) : fmaxf(v1, p);
            p = __shfl_xor(v0, 4, 16); v0 = a2 ? fmaxf(v0, p) : fminf(v0, p);
            p = __shfl_xor(v1, 4, 16); v1 = a2 ? fminf(v1, p) : fmaxf(v1, p);
            p = __shfl_xor(v0, 2, 16); v0 = a1 ? fmaxf(v0, p) : fminf(v0, p);
            p = __shfl_xor(v1, 2, 16); v1 = a1 ? fminf(v1, p) : fmaxf(v1, p);
            p = __shfl_xor(v0, 1, 16); v0 = a0 ? fmaxf(v0, p) : fminf(v0, p);
            p = __shfl_xor(v1, 1, 16); v1 = a0 ? fminf(v1, p) : fmaxf(v1, p);
            // k=32: d=16 in-lane swap (bit5=0 -> descending merge)
            { float t = fmaxf(v0, v1); v1 = fminf(v0, v1); v0 = t; }
            // k=32: d=8..1 (keepmax = a_d, both regs)
            p = __shfl_xor(v0, 8, 16); v0 = a3 ? fmaxf(v0, p) : fminf(v0, p);
            p = __shfl_xor(v1, 8, 16); v1 = a3 ? fmaxf(v1, p) : fminf(v1, p);
            p = __shfl_xor(v0, 4, 16); v0 = a2 ? fmaxf(v0, p) : fminf(v0, p);
            p = __shfl_xor(v1, 4, 16); v1 = a2 ? fmaxf(v1, p) : fminf(v1, p);
            p = __shfl_xor(v0, 2, 16); v0 = a1 ? fmaxf(v0, p) : fminf(v0, p);
            p = __shfl_xor(v1, 2, 16); v1 = a1 ? fmaxf(v1, p) : fminf(v1, p);
            p = __shfl_xor(v0, 1, 16); v0 = a0 ? fmaxf(v0, p) : fminf(v0, p);
            p = __shfl_xor(v1, 1, 16); v1 = a0 ? fmaxf(v1, p) : fminf(v1, p);
            // v0 = z_sorted[lrow], v1 = z_sorted[16+lrow] (descending)
            // inclusive cumsum across e = 0..31
            float c0 = v0;
            p = __shfl_up(c0, 1, 16); c0 += (lrow >= 1) ? p : 0.f;
            p = __shfl_up(c0, 2, 16); c0 += (lrow >= 2) ? p : 0.f;
            p = __shfl_up(c0, 4, 16); c0 += (lrow >= 4) ? p : 0.f;
            p = __shfl_up(c0, 8, 16); c0 += (lrow >= 8) ? p : 0.f;
            float c1 = v1;
            p = __shfl_up(c1, 1, 16); c1 += (lrow >= 1) ? p : 0.f;
            p = __shfl_up(c1, 2, 16); c1 += (lrow >= 2) ? p : 0.f;
            p = __shfl_up(c1, 4, 16); c1 += (lrow >= 4) ? p : 0.f;
            p = __shfl_up(c1, 8, 16); c1 += (lrow >= 8) ? p : 0.f;
            c1 += __shfl(c0, 15, 16);
            // tau = max_k (cum_k - 1)/k  (proven identity, tie-robust)
            float t0 = (c0 - 1.f) * rk0;
            float t1 = (c1 - 1.f) * rk1;
            float m = fmaxf(t0, t1);
            m = fmaxf(m, __shfl_xor(m, 1, 16));
            m = fmaxf(m, __shfl_xor(m, 2, 16));
            m = fmaxf(m, __shfl_xor(m, 4, 16));
            m = fmaxf(m, __shfl_xor(m, 8, 16));
            // w from untouched originals; write bf16 to w_s
            int row = wave * 16 + quad * 4 + r;
            float w0 = fmaxf(sacc[0][r] - m, 0.f);
            float w1 = fmaxf(sacc[1][r] - m, 0.f);
            w_s[row * 40 + lrow]      = f2bf(w0);
            w_s[row * 40 + 16 + lrow] = f2bf(w1);
        }
    }
    __syncthreads();

    // ---- phase 4: out = 0.5*(W_0 V_0 + W_1 V_1); wgt writeback from LDS ----
    #pragma unroll
    for (int tt = 0; tt < 4; ++tt) {
        int ti = wave * 4 + tt;               // 0..15 = it(2) x dt(8)
        int it = ti >> 3, dt = ti & 7;
        f32x4 acc = {0.f, 0.f, 0.f, 0.f};
        #pragma unroll
        for (int h = 0; h < 2; ++h) {
            int vrow = h * 128 + dt * 16 + lrow;
            bf16x8 aw = *(const bf16x8*)&w_s[(h * 32 + it * 16 + lrow) * 40 + quad * 8];
            bf16x8 bv = *(const bf16x8*)&vT_s[VSWZ(vrow, quad * 8)];
            acc = __builtin_amdgcn_mfma_f32_16x16x32_bf16(aw, bv, acc, 0, 0, 0);
        }
        #pragma unroll
        for (int r = 0; r < 4; ++r)
            out[((size_t)b * 32 + it * 16 + quad * 4 + r) * 128 + dt * 16 + lrow] = acc[r] * 0.5f;
    }
    // wgt[node i][j][h]: thread t -> i = t>>3, j = (t&7)*4..+3, both heads.
    {
        int i  = tid >> 3;
        int j2 = (tid & 7) * 4;
        bf16x4 a0 = *(const bf16x4*)&w_s[i * 40 + j2];         // h=0
        bf16x4 a1 = *(const bf16x4*)&w_s[(32 + i) * 40 + j2];  // h=1
        float4 o0, o1;
        o0.x = bf2f(a0[0]); o0.y = bf2f(a1[0]); o0.z = bf2f(a0[1]); o0.w = bf2f(a1[1]);
        o1.x = bf2f(a0[2]); o1.y = bf2f(a1[2]); o1.z = bf2f(a0[3]); o1.w = bf2f(a1[3]);
        float* wp = &wgt[((size_t)b * 32 + i) * 64 + j2 * 2];
        *(float4*)wp = o0;
        *(float4*)(wp + 4) = o1;
    }
}

extern "C" void kernel_launch(void* const* d_in, const int* in_sizes, int n_in,
                              void* d_out, int out_size, void* d_ws, size_t ws_size,
                              hipStream_t stream) {
    const float* x  = (const float*)d_in[0];  // [4096,32,128] fp32
    const float* WK = (const float*)d_in[1];  // [128,256] fp32
    const float* WV = (const float*)d_in[2];
    const float* WQ = (const float*)d_in[3];
    float* out = (float*)d_out;               // [131072,128] fp32
    float* wgt = out + (size_t)NG * 32 * 128; // [131072,32,2] fp32
    short* pm = (short*)d_ws;                 // 32768 bf16 = 65536 B
    short* pv = pm + 32768;                   // 32768 bf16 = 65536 B

    hipLaunchKernelGGL(pack_mv_kernel, dim3(256), dim3(256), 0, stream, WQ, WK, WV, pm, pv);
    hipLaunchKernelGGL(fused_attn_kernel, dim3(NG), dim3(256), 0, stream, x, pm, pv, out, wgt);
}